// Round 4
// baseline (1140.144 us; speedup 1.0000x reference)
//
#include <hip/hip_runtime.h>
#include <hip/hip_bf16.h>

typedef __hip_bfloat16 bf16;
typedef __attribute__((ext_vector_type(8))) short short8;
typedef __attribute__((ext_vector_type(4))) float f32x4;

#define S_LEN 512
#define DIM   512
#define BATCH 128
#define ROWS  (BATCH * S_LEN)

__device__ inline unsigned short f2bu(float f){
    bf16 h = __float2bfloat16(f);
    return *reinterpret_cast<unsigned short*>(&h);
}
// dtype-flag load: f32!=0 -> fp32 array, else bf16 array
__device__ inline float ld_in(const void* p, size_t i, int f32){
    return f32 ? ((const float*)p)[i] : __bfloat162float(((const bf16*)p)[i]);
}

// ---------------------------------------------------------------------------
// dtype detector: if x is fp32, the low 16 bits of each word are mantissa bits
// -> as-bf16 exponent field is uniform-random -> 0xFF appears w.p. ~1-e^-32
// over 8192 words. If x is genuine bf16 (Gaussian data), even-index elements
// are real bf16 values -> exponent never 0xFF. flag: 1=fp32, 0=bf16.
// ---------------------------------------------------------------------------
__global__ void detect_dtype(const unsigned int* __restrict__ x, int* __restrict__ flag)
{
    __shared__ int cnt;
    if (threadIdx.x == 0) cnt = 0;
    __syncthreads();
    int loc = 0;
    for (int i = threadIdx.x; i < 8192; i += 256)
        if (((x[i] >> 7) & 0xFFu) == 0xFFu) loc++;
    atomicAdd(&cnt, loc);
    __syncthreads();
    if (threadIdx.x == 0) *flag = (cnt > 0) ? 1 : 0;
}

// ---------------------------------------------------------------------------
// converters: any-dtype 512x512 matrix -> bf16 (transposed / straight copy)
// ---------------------------------------------------------------------------
__global__ void conv_tr(const void* __restrict__ in, bf16* __restrict__ outp,
                        const int* __restrict__ flagp)
{
    const int f32 = *flagp;
    __shared__ unsigned short tile[32][33];
    const int bx = blockIdx.x, by = blockIdx.y;
    const int tx = threadIdx.x, ty = threadIdx.y;   // 32 x 8
    #pragma unroll
    for (int j = 0; j < 32; j += 8)
        tile[ty + j][tx] = f2bu(ld_in(in, (size_t)(by*32 + ty + j)*DIM + bx*32 + tx, f32));
    __syncthreads();
    #pragma unroll
    for (int j = 0; j < 32; j += 8) {
        unsigned short u = tile[tx][ty + j];
        outp[(size_t)(bx*32 + ty + j)*DIM + by*32 + tx] = *reinterpret_cast<bf16*>(&u);
    }
}

__global__ void conv_cp(const void* __restrict__ in, bf16* __restrict__ outp,
                        const int* __restrict__ flagp)
{
    const int f32 = *flagp;
    const size_t i = (size_t)blockIdx.x*256 + threadIdx.x;   // 262144 total
    outp[i] = __float2bfloat16(ld_in(in, i, f32));
}

// ---------------------------------------------------------------------------
// dvec[n] = sum_k bv[k]*Wo[k][n] + bo[n] = sum_k bv[k]*WoT[n][k] + bo[n]
// bvec[n] = dvec[n] + bi[n]
// ---------------------------------------------------------------------------
__global__ void cvec_kernel(const bf16* __restrict__ WoT, const void* __restrict__ bv,
                            const void* __restrict__ bo, const void* __restrict__ bi,
                            const int* __restrict__ flagp,
                            float* __restrict__ dvec, float* __restrict__ bvec)
{
    const int f32 = *flagp;
    const int n = threadIdx.x;      // 512 threads
    float acc = 0.f;
    for (int k = 0; k < DIM; ++k)
        acc += ld_in(bv, k, f32) * __bfloat162float(WoT[(size_t)n*DIM + k]);
    const float dd = acc + ld_in(bo, n, f32);
    dvec[n] = dd;
    bvec[n] = dd + ld_in(bi, n, f32);
}

// ---------------------------------------------------------------------------
// Shared MFMA tile core (128x128 tile, 16x16x32 bf16). Verified fragment maps:
// A[m=lane&15][k=(lane>>4)*8+j], B^T staged as [n][k], C/D col=lane&15,
// row=(lane>>4)*4+reg (learn_hip m89/m91).
// ---------------------------------------------------------------------------
#define TILE_PROLOGUE                                                          \
    __shared__ __align__(16) unsigned short As[128][72];                       \
    __shared__ __align__(16) unsigned short Bs[128][72];                       \
    const int tid  = threadIdx.x;                                              \
    const int lane = tid & 63;                                                 \
    const int wave = tid >> 6;                                                 \
    const int wm = (wave & 1) * 64;                                            \
    const int wn = (wave >> 1) * 64;                                           \
    const int cn = lane & 15;                                                  \
    const int quad = lane >> 4;                                                \
    f32x4 acc[4][4];                                                           \
    _Pragma("unroll")                                                          \
    for (int i = 0; i < 4; ++i)                                                \
        _Pragma("unroll")                                                      \
        for (int j = 0; j < 4; ++j) acc[i][j] = (f32x4){0.f,0.f,0.f,0.f};

#define TILE_MFMA                                                              \
        __syncthreads();                                                       \
        _Pragma("unroll")                                                      \
        for (int ks = 0; ks < 64; ks += 32) {                                  \
            short8 af[4], bfr[4];                                              \
            const int koff = ks + quad*8;                                      \
            _Pragma("unroll")                                                  \
            for (int i = 0; i < 4; ++i) af[i]  = *(const short8*)&As[wm + i*16 + cn][koff]; \
            _Pragma("unroll")                                                  \
            for (int j = 0; j < 4; ++j) bfr[j] = *(const short8*)&Bs[wn + j*16 + cn][koff]; \
            _Pragma("unroll")                                                  \
            for (int i = 0; i < 4; ++i)                                        \
                _Pragma("unroll")                                              \
                for (int j = 0; j < 4; ++j)                                    \
                    acc[i][j] = __builtin_amdgcn_mfma_f32_16x16x32_bf16(af[i], bfr[j], acc[i][j], 0, 0, 0); \
        }                                                                      \
        __syncthreads();

#define STAGE_B(Bt, C0)                                                        \
        {                                                                      \
            int r = tid >> 3; const int c = (tid & 7) * 8;                     \
            _Pragma("unroll")                                                  \
            for (int p = 0; p < 4; ++p, r += 32) {                             \
                uint4 v = *(const uint4*)((Bt) + (size_t)((C0) + r)*DIM + k0 + c); \
                *(uint4*)&Bs[r][c] = v;                                        \
            }                                                                  \
        }

// A-stage from dtype-flagged global array at element index base (8 elems)
#define STAGE_A_IN(SRC, BASE)                                                  \
                if (f32) {                                                     \
                    const float* sp = (const float*)(SRC) + (BASE);            \
                    float4 a = *(const float4*)sp;                             \
                    float4 b = *(const float4*)(sp + 4);                       \
                    __align__(16) unsigned short w[8];                         \
                    w[0]=f2bu(a.x); w[1]=f2bu(a.y); w[2]=f2bu(a.z); w[3]=f2bu(a.w); \
                    w[4]=f2bu(b.x); w[5]=f2bu(b.y); w[6]=f2bu(b.z); w[7]=f2bu(b.w); \
                    *(uint4*)&As[r][c] = *(const uint4*)w;                     \
                } else {                                                       \
                    *(uint4*)&As[r][c] = *(const uint4*)((const bf16*)(SRC) + (BASE)); \
                }

// ---------------------------------------------------------------------------
// gemm_sq: C = A @ B; A row-major [m][k] bf16, B transposed [n][k] bf16.
// Writes normal (Pout) and transposed (Tout). M=N=K=512, grid(4,4).
// ---------------------------------------------------------------------------
__global__ __launch_bounds__(256) void gemm_sq(const bf16* __restrict__ A,
        const bf16* __restrict__ Btm, bf16* __restrict__ Pout, bf16* __restrict__ Tout)
{
    TILE_PROLOGUE
    const int R0 = blockIdx.y * 128;
    const int C0 = blockIdx.x * 128;
    for (int k0 = 0; k0 < DIM; k0 += 64) {
        {
            int r = tid >> 3; const int c = (tid & 7) * 8;
            #pragma unroll
            for (int p = 0; p < 4; ++p, r += 32)
                *(uint4*)&As[r][c] = *(const uint4*)(A + (size_t)(R0 + r)*DIM + k0 + c);
        }
        STAGE_B(Btm, C0)
        TILE_MFMA
    }
    #pragma unroll
    for (int i = 0; i < 4; ++i) {
        const int rowb = R0 + wm + i*16 + quad*4;
        #pragma unroll
        for (int j = 0; j < 4; ++j) {
            const int cc = C0 + wn + j*16 + cn;
            #pragma unroll
            for (int rr = 0; rr < 4; ++rr) {
                const float v = acc[i][j][rr];
                Pout[(size_t)(rowb + rr)*DIM + cc] = __float2bfloat16(v);
                Tout[(size_t)cc*DIM + rowb + rr]  = __float2bfloat16(v);
            }
        }
    }
}

// ---------------------------------------------------------------------------
// gemm_xf_chunk: U = X[chunk] @ Wi + bvec (fp32 out). grid(4, CR/128).
// X is the raw input (dtype via flag); chunk start passed as element offset.
// ---------------------------------------------------------------------------
__global__ __launch_bounds__(256) void gemm_xf_chunk(const void* __restrict__ X,
        size_t eoff, const bf16* __restrict__ WiT, const float* __restrict__ bvec,
        const int* __restrict__ flagp, float* __restrict__ U)
{
    const int f32 = *flagp;
    TILE_PROLOGUE
    const int R0 = blockIdx.y * 128;
    const int C0 = blockIdx.x * 128;
    for (int k0 = 0; k0 < DIM; k0 += 64) {
        {
            int r = tid >> 3; const int c = (tid & 7) * 8;
            #pragma unroll
            for (int p = 0; p < 4; ++p, r += 32) {
                const size_t base = eoff + (size_t)(R0 + r)*DIM + k0 + c;
                STAGE_A_IN(X, base)
            }
        }
        STAGE_B(WiT, C0)
        TILE_MFMA
    }
    #pragma unroll
    for (int i = 0; i < 4; ++i) {
        const int rowb = R0 + wm + i*16 + quad*4;
        #pragma unroll
        for (int j = 0; j < 4; ++j) {
            const int cc = C0 + wn + j*16 + cn;
            const float bb = bvec[cc];
            #pragma unroll
            for (int rr = 0; rr < 4; ++rr)
                U[(size_t)(rowb + rr)*DIM + cc] = acc[i][j][rr] + bb;
        }
    }
}

// ---------------------------------------------------------------------------
// gemm_row0: U0[b][n] = X[b,0,:] @ Wi + bvec. M=128 rows at stride S*D. grid(4,1).
// ---------------------------------------------------------------------------
__global__ __launch_bounds__(256) void gemm_row0(const void* __restrict__ X,
        const bf16* __restrict__ WiT, const float* __restrict__ bvec,
        const int* __restrict__ flagp, float* __restrict__ U0)
{
    const int f32 = *flagp;
    TILE_PROLOGUE
    const int C0 = blockIdx.x * 128;
    for (int k0 = 0; k0 < DIM; k0 += 64) {
        {
            int r = tid >> 3; const int c = (tid & 7) * 8;
            #pragma unroll
            for (int p = 0; p < 4; ++p, r += 32) {
                const size_t base = (size_t)r*S_LEN*DIM + k0 + c;
                STAGE_A_IN(X, base)
            }
        }
        STAGE_B(WiT, C0)
        TILE_MFMA
    }
    #pragma unroll
    for (int i = 0; i < 4; ++i) {
        const int rowb = wm + i*16 + quad*4;
        #pragma unroll
        for (int j = 0; j < 4; ++j) {
            const int cc = C0 + wn + j*16 + cn;
            const float bb = bvec[cc];
            #pragma unroll
            for (int rr = 0; rr < 4; ++rr)
                U0[(size_t)(rowb + rr)*DIM + cc] = acc[i][j][rr] + bb;
        }
    }
}

// ---------------------------------------------------------------------------
// gemm_v0: V0 = U0 + (U0 - d) @ W.  B-op = T0 = W^T. M=128, grid(4,1).
// ---------------------------------------------------------------------------
__global__ __launch_bounds__(256) void gemm_v0(const float* __restrict__ U0,
        const bf16* __restrict__ T0, const float* __restrict__ dvec, float* __restrict__ V0)
{
    TILE_PROLOGUE
    const int C0 = blockIdx.x * 128;
    for (int k0 = 0; k0 < DIM; k0 += 64) {
        {
            int r = tid >> 3; const int c = (tid & 7) * 8;
            #pragma unroll
            for (int p = 0; p < 4; ++p, r += 32) {
                __align__(16) unsigned short w[8];
                #pragma unroll
                for (int q = 0; q < 8; ++q)
                    w[q] = f2bu(U0[(size_t)r*DIM + k0 + c + q] - dvec[k0 + c + q]);
                *(uint4*)&As[r][c] = *(const uint4*)w;
            }
        }
        STAGE_B(T0, C0)
        TILE_MFMA
    }
    #pragma unroll
    for (int i = 0; i < 4; ++i) {
        const int rowb = wm + i*16 + quad*4;
        #pragma unroll
        for (int j = 0; j < 4; ++j) {
            const int cc = C0 + wn + j*16 + cn;
            #pragma unroll
            for (int rr = 0; rr < 4; ++rr) {
                const size_t off = (size_t)(rowb + rr)*DIM + cc;
                V0[off] = acc[i][j][rr] + U0[off];
            }
        }
    }
}

// ---------------------------------------------------------------------------
// gemm_level: yout[r] = yin[r] + shifted_operand[r] @ W^shift   (yin fp32)
// mode=1 (shift=1): t==0 -> operand = yin[row]-d; t==1 -> operand = V0c.
// mode=0: operand = yin[row-shift] if t>=shift else 0.
// TO_OUT: store to d_out (dtype via flag) at element offset eoff+off.
// ---------------------------------------------------------------------------
template<bool TO_OUT>
__global__ __launch_bounds__(256) void gemm_level(const float* __restrict__ yin,
        void* __restrict__ yout, size_t eoff, const bf16* __restrict__ Bt,
        const float* __restrict__ dvec, const float* __restrict__ V0c,
        const int* __restrict__ flagp, const int shift, const int mode)
{
    const int f32 = *flagp;
    TILE_PROLOGUE
    const int R0 = blockIdx.y * 128;
    const int C0 = blockIdx.x * 128;
    for (int k0 = 0; k0 < DIM; k0 += 64) {
        {
            int r = tid >> 3; const int c = (tid & 7) * 8;
            #pragma unroll
            for (int p = 0; p < 4; ++p, r += 32) {
                const int row = R0 + r;
                const int t = row & (S_LEN - 1);
                __align__(16) unsigned short w[8];
                if (mode && t == 1) {
                    const float* vp = V0c + (size_t)(row >> 9)*DIM + k0 + c;
                    #pragma unroll
                    for (int q = 0; q < 8; ++q) w[q] = f2bu(vp[q]);
                } else if (mode && t == 0) {
                    const float* sp = yin + (size_t)row*DIM + k0 + c;
                    #pragma unroll
                    for (int q = 0; q < 8; ++q) w[q] = f2bu(sp[q] - dvec[k0 + c + q]);
                } else if (t >= shift) {
                    const float* sp = yin + (size_t)(row - shift)*DIM + k0 + c;
                    #pragma unroll
                    for (int q = 0; q < 8; ++q) w[q] = f2bu(sp[q]);
                } else {
                    #pragma unroll
                    for (int q = 0; q < 8; ++q) w[q] = 0;
                }
                *(uint4*)&As[r][c] = *(const uint4*)w;
            }
        }
        STAGE_B(Bt, C0)
        TILE_MFMA
    }
    #pragma unroll
    for (int i = 0; i < 4; ++i) {
        const int rowb = R0 + wm + i*16 + quad*4;
        #pragma unroll
        for (int j = 0; j < 4; ++j) {
            const int cc = C0 + wn + j*16 + cn;
            #pragma unroll
            for (int rr = 0; rr < 4; ++rr) {
                const size_t off = (size_t)(rowb + rr)*DIM + cc;
                const float v = acc[i][j][rr] + yin[off];
                if (TO_OUT) {
                    if (f32) ((float*)yout)[eoff + off] = v;
                    else     ((bf16*)yout)[eoff + off] = __float2bfloat16(v);
                } else {
                    ((float*)yout)[off] = v;
                }
            }
        }
    }
}

// final_state[b,:] = outputs[b, len_b - 1, :]  (dtype via flag)
__global__ void gather_final(void* __restrict__ out, const int* __restrict__ lens,
                             const int* __restrict__ flagp)
{
    const int f32 = *flagp;
    const int idx = blockIdx.x * 256 + threadIdx.x;   // 65536
    const int b = idx >> 9, n = idx & 511;
    int L = lens[b];
    if (L < 1) L = 1;
    if (L > S_LEN) L = S_LEN;
    const size_t src = ((size_t)b*S_LEN + (L - 1))*DIM + n;
    const size_t dst = (size_t)ROWS*DIM + idx;
    if (f32) ((float*)out)[dst] = ((const float*)out)[src];
    else     ((bf16*)out)[dst]  = ((const bf16*)out)[src];
}

// ---------------------------------------------------------------------------
extern "C" void kernel_launch(void* const* d_in, const int* in_sizes, int n_in,
                              void* d_out, int out_size, void* d_ws, size_t ws_size,
                              hipStream_t stream)
{
    const void* X  = d_in[0];
    const void* Wi = d_in[1];
    const void* bi = d_in[2];
    // d_in[3..6] = Wq, bq, Wk, bk — dead (softmax over singleton axis == 1)
    const void* Wv = d_in[7];
    const void* bv = d_in[8];
    const void* Wo = d_in[9];
    const void* bo = d_in[10];
    const int* lens = (const int*)d_in[11];
    char* ws = (char*)d_ws;

    // ---- fixed workspace layout (~5.3 MB) ----
    const size_t MATB = (size_t)DIM * DIM * sizeof(bf16);    // 524288
    bf16* WiT = (bf16*)(ws + 0*MATB);
    bf16* WoT = (bf16*)(ws + 1*MATB);
    bf16* Wvb = (bf16*)(ws + 2*MATB);
    bf16* S2  = (bf16*)(ws + 3*MATB);   // W, then W^4
    bf16* S3  = (bf16*)(ws + 4*MATB);   // W^2, then W^8
    bf16* T0  = (bf16*)(ws + 5*MATB);   // W^T
    bf16* T1  = (bf16*)(ws + 6*MATB);   // (W^2)^T
    bf16* T2  = (bf16*)(ws + 7*MATB);   // (W^4)^T
    bf16* T3  = (bf16*)(ws + 8*MATB);   // (W^8)^T
    float* dvec = (float*)(ws + 9*MATB);
    float* bvec = dvec + DIM;
    int*   flag = (int*)(bvec + DIM);
    float* U0   = (float*)(flag + 64);              // 128*512 f32
    float* V0   = U0 + (size_t)BATCH*DIM;           // 128*512 f32
    char*  dyn  = (char*)(V0 + (size_t)BATCH*DIM);
    const size_t fixed = (size_t)(dyn - ws);
    const size_t avail = ws_size > fixed ? ws_size - fixed : 0;

    // largest chunk whose fp32 ping-pong fits the remaining workspace
    int CR = 512;
    for (int cr = 65536; cr >= 512; cr >>= 1)
        if ((size_t)2*cr*DIM*4 <= avail) { CR = cr; break; }

    detect_dtype<<<1, 256, 0, stream>>>((const unsigned int*)X, flag);
    conv_tr<<<dim3(16,16), dim3(32,8), 0, stream>>>(Wi, WiT, flag);
    conv_tr<<<dim3(16,16), dim3(32,8), 0, stream>>>(Wo, WoT, flag);
    conv_cp<<<1024, 256, 0, stream>>>(Wv, Wvb, flag);
    cvec_kernel<<<1, DIM, 0, stream>>>(WoT, bv, bo, bi, flag, dvec, bvec);
    gemm_sq<<<dim3(4,4), 256, 0, stream>>>(Wvb, WoT, S2, T0);   // W
    gemm_sq<<<dim3(4,4), 256, 0, stream>>>(S2, T0, S3, T1);     // W^2
    gemm_sq<<<dim3(4,4), 256, 0, stream>>>(S3, T1, S2, T2);     // W^4
    gemm_sq<<<dim3(4,4), 256, 0, stream>>>(S2, T2, S3, T3);     // W^8
    gemm_row0<<<dim3(4,1), 256, 0, stream>>>(X, WiT, bvec, flag, U0);
    gemm_v0<<<dim3(4,1), 256, 0, stream>>>(U0, T0, dvec, V0);

    float* bufA = (float*)dyn;
    float* bufB = bufA + (size_t)CR*DIM;
    const int NC = ROWS / CR;
    const int RT = CR / 128;
    for (int c = 0; c < NC; ++c) {
        const size_t eoff = (size_t)c*CR*DIM;
        const float* V0c = V0 + (size_t)(c*(CR/S_LEN))*DIM;
        gemm_xf_chunk<<<dim3(4,RT), 256, 0, stream>>>(X, eoff, WiT, bvec, flag, bufA);
        gemm_level<false><<<dim3(4,RT), 256, 0, stream>>>(bufA, bufB, 0, T0, dvec, V0c, flag, 1, 1);
        gemm_level<false><<<dim3(4,RT), 256, 0, stream>>>(bufB, bufA, 0, T1, dvec, V0c, flag, 2, 0);
        gemm_level<false><<<dim3(4,RT), 256, 0, stream>>>(bufA, bufB, 0, T2, dvec, V0c, flag, 4, 0);
        gemm_level<true ><<<dim3(4,RT), 256, 0, stream>>>(bufB, d_out, eoff, T3, dvec, V0c, flag, 8, 0);
    }
    gather_final<<<256, 256, 0, stream>>>(d_out, lens, flag);
}